// Round 8
// baseline (418.480 us; speedup 1.0000x reference)
//
#include <hip/hip_runtime.h>

#define D_IN  256
#define D_HID 512
#define NEG_SLOPE 0.2f
#define SCAN_CHUNK 2048

typedef __attribute__((ext_vector_type(8))) short short8;
typedef __attribute__((ext_vector_type(4))) float floatx4;

__device__ __forceinline__ unsigned short f2bf(float f) {
    unsigned int u = __float_as_uint(f);
    u += 0x7fffu + ((u >> 16) & 1u);   // round-to-nearest-even
    return (unsigned short)(u >> 16);
}
__device__ __forceinline__ float bf2f(unsigned short u) {
    return __uint_as_float(((unsigned int)u) << 16);
}

__device__ __forceinline__ int eidx(const void* ei, long pos, int is64) {
    return is64 ? (int)((const long long*)ei)[pos] : ((const int*)ei)[pos];
}

// ---- init: convert x -> bf16, zero deg, detect edge dtype (block 0) ----
__global__ __launch_bounds__(256) void k_init(const float* __restrict__ x,
                                              unsigned short* __restrict__ xb,
                                              int* __restrict__ deg, int N,
                                              const unsigned int* __restrict__ ei,
                                              int npairs, int* flag) {
    long t = (long)blockIdx.x * blockDim.x + threadIdx.x;
    long i = t * 4;
    long tot = (long)N * D_IN;
    if (i < tot) {
        float4 v = *(const float4*)(x + i);
        ushort4 o;
        o.x = f2bf(v.x); o.y = f2bf(v.y); o.z = f2bf(v.z); o.w = f2bf(v.w);
        *(ushort4*)(xb + i) = o;
    }
    if (t < N) deg[t] = 0;
    if (blockIdx.x == 0) {
        __shared__ int nz;
        if (threadIdx.x == 0) nz = 0;
        __syncthreads();
        for (int p = threadIdx.x; p < npairs; p += blockDim.x)
            if (ei[2 * p + 1] != 0) nz = 1;
        __syncthreads();
        if (threadIdx.x == 0) *flag = nz ? 0 : 1;   // 1 => int64
    }
}

// ---- degree count (int only) ----
__global__ void k_deg_count(const void* __restrict__ ei, const int* __restrict__ flag,
                            int* __restrict__ deg, int E) {
    int e = blockIdx.x * blockDim.x + threadIdx.x;
    if (e < E) atomicAdd(&deg[eidx(ei, (long)E + e, *flag)], 1);
}

// ---- hierarchical scan ----
__global__ __launch_bounds__(256) void k_scan1(const int* __restrict__ deg,
                                               int* __restrict__ bsum, int N) {
    int base = blockIdx.x * SCAN_CHUNK;
    int hi = min(base + SCAN_CHUNK, N);
    int s = 0;
    for (int i = base + threadIdx.x; i < hi; i += 256) s += deg[i];
#pragma unroll
    for (int off = 32; off > 0; off >>= 1) s += __shfl_down(s, off, 64);
    __shared__ int lds[4];
    if ((threadIdx.x & 63) == 0) lds[threadIdx.x >> 6] = s;
    __syncthreads();
    if (threadIdx.x == 0) bsum[blockIdx.x] = lds[0] + lds[1] + lds[2] + lds[3];
}

__global__ __launch_bounds__(1024) void k_scan2(const int* __restrict__ bsum,
                                                int* __restrict__ bbase,
                                                int* __restrict__ offs, int NB, int N) {
    __shared__ int lds[1024];
    int t = threadIdx.x;
    lds[t] = (t < NB) ? bsum[t] : 0;
    __syncthreads();
    for (int d = 1; d < 1024; d <<= 1) {
        int add = (t >= d) ? lds[t - d] : 0;
        __syncthreads();
        lds[t] += add;
        __syncthreads();
    }
    if (t < NB) bbase[t] = (t > 0) ? lds[t - 1] : 0;
    if (t == 0) offs[N] = lds[NB - 1];
}

__global__ __launch_bounds__(256) void k_scan3(const int* __restrict__ deg,
                                               const int* __restrict__ bbase,
                                               int* __restrict__ offs,
                                               int* __restrict__ cursor,
                                               float* __restrict__ dinv, int N) {
    __shared__ int lds[256];
    int base = blockIdx.x * SCAN_CHUNK;
    int t = threadIdx.x;
    int lo = base + t * 8;
    int v[8], s = 0;
#pragma unroll
    for (int j = 0; j < 8; ++j) {
        int i = lo + j;
        v[j] = (i < N) ? deg[i] : 0;
        s += v[j];
    }
    lds[t] = s;
    __syncthreads();
    for (int d = 1; d < 256; d <<= 1) {
        int add = (t >= d) ? lds[t - d] : 0;
        __syncthreads();
        lds[t] += add;
        __syncthreads();
    }
    int run = bbase[blockIdx.x] + ((t > 0) ? lds[t - 1] : 0);
#pragma unroll
    for (int j = 0; j < 8; ++j) {
        int i = lo + j;
        if (i < N) {
            offs[i] = run; cursor[i] = run;
            dinv[i] = rsqrtf(1.0f + (float)v[j]);
            run += v[j];
        }
    }
}

// ---- fill CSR edge list (src per slot, dst-sorted) ----
__global__ void k_fill(const void* __restrict__ ei, const int* __restrict__ flag,
                       int* __restrict__ cursor, int* __restrict__ esrc, int E) {
    int e = blockIdx.x * blockDim.x + threadIdx.x;
    if (e >= E) return;
    int is64 = *flag;
    int s = eidx(ei, e, is64), d = eidx(ei, (long)E + e, is64);
    int pos = atomicAdd(&cursor[d], 1);
    esrc[pos] = s;
}

// ---- gather (bf16 rows), 4-edge unroll ----
__global__ __launch_bounds__(256) void k_gather(const unsigned short* __restrict__ xb,
                                                const int* __restrict__ offs,
                                                const int* __restrict__ esrc,
                                                const float* __restrict__ dinv,
                                                unsigned short* __restrict__ aggb, int N) {
    int node = blockIdx.x * 4 + (threadIdx.x >> 6);
    int lane = threadIdx.x & 63;
    if (node >= N) return;
    float di = dinv[node];
    ushort4 u0 = ((const ushort4*)xb)[(long)node * 64 + lane];
    float ax = di * bf2f(u0.x), ay = di * bf2f(u0.y), az = di * bf2f(u0.z), aw = di * bf2f(u0.w);
    int beg = offs[node], end = offs[node + 1];
    int e = beg;
    for (; e + 3 < end; e += 4) {   // 4 row-loads in flight
        int s0 = esrc[e], s1 = esrc[e + 1], s2 = esrc[e + 2], s3 = esrc[e + 3];
        float w0 = dinv[s0], w1 = dinv[s1], w2 = dinv[s2], w3 = dinv[s3];
        ushort4 a = ((const ushort4*)xb)[(long)s0 * 64 + lane];
        ushort4 b = ((const ushort4*)xb)[(long)s1 * 64 + lane];
        ushort4 c = ((const ushort4*)xb)[(long)s2 * 64 + lane];
        ushort4 d = ((const ushort4*)xb)[(long)s3 * 64 + lane];
        ax += w0 * bf2f(a.x) + w1 * bf2f(b.x) + w2 * bf2f(c.x) + w3 * bf2f(d.x);
        ay += w0 * bf2f(a.y) + w1 * bf2f(b.y) + w2 * bf2f(c.y) + w3 * bf2f(d.y);
        az += w0 * bf2f(a.z) + w1 * bf2f(b.z) + w2 * bf2f(c.z) + w3 * bf2f(d.z);
        aw += w0 * bf2f(a.w) + w1 * bf2f(b.w) + w2 * bf2f(c.w) + w3 * bf2f(d.w);
    }
    for (; e < end; ++e) {
        int s0 = esrc[e];
        float w0 = dinv[s0];
        ushort4 a = ((const ushort4*)xb)[(long)s0 * 64 + lane];
        ax += w0 * bf2f(a.x); ay += w0 * bf2f(a.y);
        az += w0 * bf2f(a.z); aw += w0 * bf2f(a.w);
    }
    ax *= di; ay *= di; az *= di; aw *= di;
    ushort4 o; o.x = f2bf(ax); o.y = f2bf(ay); o.z = f2bf(az); o.w = f2bf(aw);
    ((ushort4*)aggb)[(long)node * 64 + lane] = o;
}

// ---- prep: transpose both weights to bf16 [N,K] ----
__global__ void k_prep(const float* __restrict__ W_gcn, unsigned short* __restrict__ Wgt,
                       const float* __restrict__ W2, unsigned short* __restrict__ W2t) {
    int t = blockIdx.x * blockDim.x + threadIdx.x;
    if (t < D_IN * D_HID) {                       // Wgt [512,256]
        int n = t / D_IN, k = t - n * D_IN;
        Wgt[t] = f2bf(W_gcn[(long)k * D_HID + n]);
        return;
    }
    t -= D_IN * D_HID;
    if (t < D_HID * D_HID) {                      // W2t [512,512]
        int n = t / D_HID, k = t - n * D_HID;
        W2t[t] = f2bf(W2[(long)k * D_HID + n]);
    }
}

// ---- persistent-A GEMM, 64-row M-tile, full N=512 per block ----
// mode 0: C[row,col] = bf16(leaky(A@Bt^T + bias))          (GEMM1, K=256)
// mode 1: out[row]   = sum_col leaky(A@Bt^T + bias)*wout + b_out  (GEMM2+head, K=512)
__device__ __forceinline__ void async_cp16(const unsigned short* gp, unsigned short* lp) {
    __builtin_amdgcn_global_load_lds((const __attribute__((address_space(1))) void*)gp,
                                     (__attribute__((address_space(3))) void*)lp, 16, 0, 0);
}

__global__ __launch_bounds__(256) void k_gemm64(const unsigned short* __restrict__ A,
                                                const unsigned short* __restrict__ Bt,
                                                const float* __restrict__ bias,
                                                const float* __restrict__ wout,
                                                const float* __restrict__ bout,
                                                unsigned short* __restrict__ C,
                                                float* __restrict__ out,
                                                int M, int K, int mode) {
    __shared__ __align__(16) unsigned short As[64 * 512];      // 64 KB max (K<=512), [kc][64][32]
    __shared__ __align__(16) unsigned short Bs[2][128 * 32];   // 2 x 8 KB dbuf, [n][32]
    const int tid  = threadIdx.x;
    const int lane = tid & 63, wave = tid >> 6;
    const int m0 = blockIdx.x * 64;
    const int r = lane & 15, q = lane >> 4;
    const int wm = wave * 16;                                  // wave owns 16 rows, all cols
    const int KC = K >> 5;

    // stage whole A tile: chunk kc = rows 0..63 x k (kc*32..+32); one 256-piece round/chunk
    {
        int row = tid >> 2, qtr = tid & 3;
        int gm = m0 + row; if (gm >= M) gm = M - 1;
        const unsigned short* ap = A + (long)gm * K + qtr * 8;
        for (int kc = 0; kc < KC; ++kc)
            async_cp16(ap + kc * 32, As + kc * 2048 + tid * 8);
    }
    // stage Bs[0] for (n0=0, kc=0)
    {
        int row = tid >> 2, qtr = tid & 3;
#pragma unroll
        for (int rr = 0; rr < 2; ++rr) {
            int c = rr * 256 + tid;
            int brow = c >> 2, bq = c & 3;
            async_cp16(Bt + (long)brow * K + bq * 8, Bs[0] + c * 8);
        }
        (void)row; (void)qtr;
    }
    __syncthreads();

    float p_acc[4] = {0.f, 0.f, 0.f, 0.f};   // mode 1: per-(q,t2) row head sums
    int buf = 0;

    for (int n0i = 0; n0i < 4; ++n0i) {
        int n0 = n0i * 128;
        floatx4 acc[8];
#pragma unroll
        for (int j = 0; j < 8; ++j) acc[j] = (floatx4){0.f, 0.f, 0.f, 0.f};

        for (int kc = 0; kc < KC; ++kc) {
            // prefetch next Bs
            bool last = (n0i == 3) && (kc == KC - 1);
            if (!last) {
                int nn0i = (kc + 1 < KC) ? n0i : n0i + 1;
                int nkc  = (kc + 1 < KC) ? kc + 1 : 0;
                const unsigned short* bp = Bt + (long)(nn0i * 128) * K + nkc * 32;
#pragma unroll
                for (int rr = 0; rr < 2; ++rr) {
                    int c = rr * 256 + tid;
                    int brow = c >> 2, bq = c & 3;
                    async_cp16(bp + (long)brow * K + bq * 8, Bs[buf ^ 1] + c * 8);
                }
            }
            short8 af = *(const short8*)(As + kc * 2048 + (wm + r) * 32 + q * 8);
            short8 bf[8];
#pragma unroll
            for (int j = 0; j < 8; ++j)
                bf[j] = *(const short8*)(Bs[buf] + (j * 16 + r) * 32 + q * 8);
#pragma unroll
            for (int j = 0; j < 8; ++j)
                acc[j] = __builtin_amdgcn_mfma_f32_16x16x32_bf16(af, bf[j], acc[j], 0, 0, 0);
            __syncthreads();
            buf ^= 1;
        }

        // epilogue for this n-tile.  C/D map: col = j*16 + r, row = q*4 + t2
        if (mode == 0) {
#pragma unroll
            for (int j = 0; j < 8; ++j) {
                int col = n0 + j * 16 + r;
                float bv = bias[col];
#pragma unroll
                for (int t2 = 0; t2 < 4; ++t2) {
                    int row = m0 + wm + q * 4 + t2;
                    if (row < M) {
                        float v = acc[j][t2] + bv;
                        v = v > 0.f ? v : NEG_SLOPE * v;
                        C[(long)row * D_HID + col] = f2bf(v);
                    }
                }
            }
        } else {
            float bv[8], wv[8];
#pragma unroll
            for (int j = 0; j < 8; ++j) {
                int col = n0 + j * 16 + r;
                bv[j] = bias[col];
                wv[j] = wout[col];
            }
#pragma unroll
            for (int t2 = 0; t2 < 4; ++t2) {
                float p = 0.f;
#pragma unroll
                for (int j = 0; j < 8; ++j) {
                    float v = acc[j][t2] + bv[j];
                    v = v > 0.f ? v : NEG_SLOPE * v;
                    p += v * wv[j];
                }
                p += __shfl_xor(p, 8, 64);
                p += __shfl_xor(p, 4, 64);
                p += __shfl_xor(p, 2, 64);
                p += __shfl_xor(p, 1, 64);
                p_acc[t2] += p;
            }
        }
    }

    if (mode == 1 && r == 0) {
        float b0 = bout[0];
#pragma unroll
        for (int t2 = 0; t2 < 4; ++t2) {
            int row = m0 + wm + q * 4 + t2;
            if (row < M) out[row] = p_acc[t2] + b0;   // exclusive rows: plain store
        }
    }
}

extern "C" void kernel_launch(void* const* d_in, const int* in_sizes, int n_in,
                              void* d_out, int out_size, void* d_ws, size_t ws_size,
                              hipStream_t stream) {
    const float* x     = (const float*)d_in[0];
    const void*  ei    = d_in[1];
    const float* W_gcn = (const float*)d_in[2];
    const float* b_gcn = (const float*)d_in[3];
    const float* W2    = (const float*)d_in[4];
    const float* b2    = (const float*)d_in[5];
    const float* W_out = (const float*)d_in[6];
    const float* b_out = (const float*)d_in[7];
    float* out = (float*)d_out;

    const int N = in_sizes[0] / D_IN;
    const int E = in_sizes[1] / 2;
    const int NB = (N + SCAN_CHUNK - 1) / SCAN_CHUNK;

    char* w = (char*)d_ws;
    size_t off = 0;
    auto alloc = [&](size_t bytes) { char* p = w + off; off = (off + bytes + 255) & ~(size_t)255; return p; };
    int*            flag   = (int*)alloc(256);
    float*          dinv   = (float*)alloc((size_t)N * 4);
    int*            deg_i  = (int*)alloc((size_t)N * 4);
    int*            offs   = (int*)alloc((size_t)(N + 1) * 4);
    int*            cursor = (int*)alloc((size_t)N * 4);
    int*            bsum   = (int*)alloc((size_t)NB * 4);
    int*            bbase  = (int*)alloc((size_t)NB * 4);
    int*            esrc   = (int*)alloc((size_t)E * 4);
    unsigned short* xb     = (unsigned short*)alloc((size_t)N * D_IN * 2);
    unsigned short* aggb   = (unsigned short*)alloc((size_t)N * D_IN * 2);
    unsigned short* h1     = (unsigned short*)alloc((size_t)N * D_HID * 2);
    unsigned short* Wgt    = (unsigned short*)alloc((size_t)D_IN * D_HID * 2);
    unsigned short* W2t    = (unsigned short*)alloc((size_t)D_HID * D_HID * 2);

    int npairs = E < 2048 ? E : 2048;
    long xthreads = ((long)N * D_IN) / 4;
    k_init<<<(unsigned)((xthreads + 255) / 256), 256, 0, stream>>>(
        x, xb, deg_i, N, (const unsigned int*)ei, npairs, flag);

    k_deg_count<<<(E + 255) / 256, 256, 0, stream>>>(ei, flag, deg_i, E);
    k_scan1<<<NB, 256, 0, stream>>>(deg_i, bsum, N);
    k_scan2<<<1, 1024, 0, stream>>>(bsum, bbase, offs, NB, N);
    k_scan3<<<NB, 256, 0, stream>>>(deg_i, bbase, offs, cursor, dinv, N);
    k_fill<<<(E + 255) / 256, 256, 0, stream>>>(ei, flag, cursor, esrc, E);
    k_gather<<<(N + 3) / 4, 256, 0, stream>>>(xb, offs, esrc, dinv, aggb, N);

    int prep_threads = D_IN * D_HID + D_HID * D_HID;
    k_prep<<<(prep_threads + 255) / 256, 256, 0, stream>>>(W_gcn, Wgt, W2, W2t);

    int gblocks = (N + 63) / 64;
    k_gemm64<<<gblocks, 256, 0, stream>>>(aggb, Wgt, b_gcn, W_out, b_out, h1, out, N, D_IN, 0);
    k_gemm64<<<gblocks, 256, 0, stream>>>(h1, W2t, b2, W_out, b_out, h1, out, N, D_HID, 1);
}

// Round 9
// 364.491 us; speedup vs baseline: 1.1481x; 1.1481x over previous
//
#include <hip/hip_runtime.h>

#define D_IN  256
#define D_HID 512
#define NEG_SLOPE 0.2f
#define SCAN_CHUNK 2048

typedef __attribute__((ext_vector_type(8))) short short8;
typedef __attribute__((ext_vector_type(4))) float floatx4;

__device__ __forceinline__ unsigned short f2bf(float f) {
    unsigned int u = __float_as_uint(f);
    u += 0x7fffu + ((u >> 16) & 1u);   // round-to-nearest-even
    return (unsigned short)(u >> 16);
}
__device__ __forceinline__ float bf2f(unsigned short u) {
    return __uint_as_float(((unsigned int)u) << 16);
}

__device__ __forceinline__ int eidx(const void* ei, long pos, int is64) {
    return is64 ? (int)((const long long*)ei)[pos] : ((const int*)ei)[pos];
}

// ---- init: convert x -> bf16, zero deg, detect edge dtype (block 0) ----
__global__ __launch_bounds__(256) void k_init(const float* __restrict__ x,
                                              unsigned short* __restrict__ xb,
                                              int* __restrict__ deg, int N,
                                              const unsigned int* __restrict__ ei,
                                              int npairs, int* flag) {
    long t = (long)blockIdx.x * blockDim.x + threadIdx.x;
    long i = t * 4;
    long tot = (long)N * D_IN;
    if (i < tot) {
        float4 v = *(const float4*)(x + i);
        ushort4 o;
        o.x = f2bf(v.x); o.y = f2bf(v.y); o.z = f2bf(v.z); o.w = f2bf(v.w);
        *(ushort4*)(xb + i) = o;
    }
    if (t < N) deg[t] = 0;
    if (blockIdx.x == 0) {
        __shared__ int nz;
        if (threadIdx.x == 0) nz = 0;
        __syncthreads();
        for (int p = threadIdx.x; p < npairs; p += blockDim.x)
            if (ei[2 * p + 1] != 0) nz = 1;
        __syncthreads();
        if (threadIdx.x == 0) *flag = nz ? 0 : 1;   // 1 => int64
    }
}

// ---- degree count (int only) ----
__global__ void k_deg_count(const void* __restrict__ ei, const int* __restrict__ flag,
                            int* __restrict__ deg, int E) {
    int e = blockIdx.x * blockDim.x + threadIdx.x;
    if (e < E) atomicAdd(&deg[eidx(ei, (long)E + e, *flag)], 1);
}

// ---- hierarchical scan ----
__global__ __launch_bounds__(256) void k_scan1(const int* __restrict__ deg,
                                               int* __restrict__ bsum, int N) {
    int base = blockIdx.x * SCAN_CHUNK;
    int hi = min(base + SCAN_CHUNK, N);
    int s = 0;
    for (int i = base + threadIdx.x; i < hi; i += 256) s += deg[i];
#pragma unroll
    for (int off = 32; off > 0; off >>= 1) s += __shfl_down(s, off, 64);
    __shared__ int lds[4];
    if ((threadIdx.x & 63) == 0) lds[threadIdx.x >> 6] = s;
    __syncthreads();
    if (threadIdx.x == 0) bsum[blockIdx.x] = lds[0] + lds[1] + lds[2] + lds[3];
}

__global__ __launch_bounds__(1024) void k_scan2(const int* __restrict__ bsum,
                                                int* __restrict__ bbase,
                                                int* __restrict__ offs, int NB, int N) {
    __shared__ int lds[1024];
    int t = threadIdx.x;
    lds[t] = (t < NB) ? bsum[t] : 0;
    __syncthreads();
    for (int d = 1; d < 1024; d <<= 1) {
        int add = (t >= d) ? lds[t - d] : 0;
        __syncthreads();
        lds[t] += add;
        __syncthreads();
    }
    if (t < NB) bbase[t] = (t > 0) ? lds[t - 1] : 0;
    if (t == 0) offs[N] = lds[NB - 1];
}

__global__ __launch_bounds__(256) void k_scan3(const int* __restrict__ deg,
                                               const int* __restrict__ bbase,
                                               int* __restrict__ offs,
                                               int* __restrict__ cursor,
                                               float* __restrict__ dinv, int N) {
    __shared__ int lds[256];
    int base = blockIdx.x * SCAN_CHUNK;
    int t = threadIdx.x;
    int lo = base + t * 8;
    int v[8], s = 0;
#pragma unroll
    for (int j = 0; j < 8; ++j) {
        int i = lo + j;
        v[j] = (i < N) ? deg[i] : 0;
        s += v[j];
    }
    lds[t] = s;
    __syncthreads();
    for (int d = 1; d < 256; d <<= 1) {
        int add = (t >= d) ? lds[t - d] : 0;
        __syncthreads();
        lds[t] += add;
        __syncthreads();
    }
    int run = bbase[blockIdx.x] + ((t > 0) ? lds[t - 1] : 0);
#pragma unroll
    for (int j = 0; j < 8; ++j) {
        int i = lo + j;
        if (i < N) {
            offs[i] = run; cursor[i] = run;
            dinv[i] = rsqrtf(1.0f + (float)v[j]);
            run += v[j];
        }
    }
}

// ---- fill CSR edge list (src per slot, dst-sorted) ----
__global__ void k_fill(const void* __restrict__ ei, const int* __restrict__ flag,
                       int* __restrict__ cursor, int* __restrict__ esrc, int E) {
    int e = blockIdx.x * blockDim.x + threadIdx.x;
    if (e >= E) return;
    int is64 = *flag;
    int s = eidx(ei, e, is64), d = eidx(ei, (long)E + e, is64);
    int pos = atomicAdd(&cursor[d], 1);
    esrc[pos] = s;
}

// ---- gather (bf16 rows), 4-edge unroll ----
__global__ __launch_bounds__(256) void k_gather(const unsigned short* __restrict__ xb,
                                                const int* __restrict__ offs,
                                                const int* __restrict__ esrc,
                                                const float* __restrict__ dinv,
                                                unsigned short* __restrict__ aggb, int N) {
    int node = blockIdx.x * 4 + (threadIdx.x >> 6);
    int lane = threadIdx.x & 63;
    if (node >= N) return;
    float di = dinv[node];
    ushort4 u0 = ((const ushort4*)xb)[(long)node * 64 + lane];
    float ax = di * bf2f(u0.x), ay = di * bf2f(u0.y), az = di * bf2f(u0.z), aw = di * bf2f(u0.w);
    int beg = offs[node], end = offs[node + 1];
    int e = beg;
    for (; e + 3 < end; e += 4) {   // 4 row-loads in flight
        int s0 = esrc[e], s1 = esrc[e + 1], s2 = esrc[e + 2], s3 = esrc[e + 3];
        float w0 = dinv[s0], w1 = dinv[s1], w2 = dinv[s2], w3 = dinv[s3];
        ushort4 a = ((const ushort4*)xb)[(long)s0 * 64 + lane];
        ushort4 b = ((const ushort4*)xb)[(long)s1 * 64 + lane];
        ushort4 c = ((const ushort4*)xb)[(long)s2 * 64 + lane];
        ushort4 d = ((const ushort4*)xb)[(long)s3 * 64 + lane];
        ax += w0 * bf2f(a.x) + w1 * bf2f(b.x) + w2 * bf2f(c.x) + w3 * bf2f(d.x);
        ay += w0 * bf2f(a.y) + w1 * bf2f(b.y) + w2 * bf2f(c.y) + w3 * bf2f(d.y);
        az += w0 * bf2f(a.z) + w1 * bf2f(b.z) + w2 * bf2f(c.z) + w3 * bf2f(d.z);
        aw += w0 * bf2f(a.w) + w1 * bf2f(b.w) + w2 * bf2f(c.w) + w3 * bf2f(d.w);
    }
    for (; e < end; ++e) {
        int s0 = esrc[e];
        float w0 = dinv[s0];
        ushort4 a = ((const ushort4*)xb)[(long)s0 * 64 + lane];
        ax += w0 * bf2f(a.x); ay += w0 * bf2f(a.y);
        az += w0 * bf2f(a.z); aw += w0 * bf2f(a.w);
    }
    ax *= di; ay *= di; az *= di; aw *= di;
    ushort4 o; o.x = f2bf(ax); o.y = f2bf(ay); o.z = f2bf(az); o.w = f2bf(aw);
    ((ushort4*)aggb)[(long)node * 64 + lane] = o;
}

// ---- prep: transpose both weights to bf16 [N,K], init outacc with bias ----
__global__ void k_prep(const float* __restrict__ W_gcn, unsigned short* __restrict__ Wgt,
                       const float* __restrict__ W2, unsigned short* __restrict__ W2t,
                       const float* __restrict__ b_out, float* __restrict__ outacc, int N) {
    int t = blockIdx.x * blockDim.x + threadIdx.x;
    if (t < D_IN * D_HID) {                       // Wgt [512,256]
        int n = t / D_IN, k = t - n * D_IN;
        Wgt[t] = f2bf(W_gcn[(long)k * D_HID + n]);
        return;
    }
    t -= D_IN * D_HID;
    if (t < D_HID * D_HID) {                      // W2t [512,512]
        int n = t / D_HID, k = t - n * D_HID;
        W2t[t] = f2bf(W2[(long)k * D_HID + n]);
        return;
    }
    t -= D_HID * D_HID;
    if (t < N) outacc[t] = b_out[0];
}

// ============ swizzled-LDS 128x128 GEMM machinery ============
// LDS tile: 128 rows x 32 k-shorts stored as 64 row-pairs x 128 B,
// 16B chunk ci within a pair stored at slot ci ^ (pair & 7).
__device__ __forceinline__ void async_cp16(const unsigned short* gp, unsigned short* lp) {
    __builtin_amdgcn_global_load_lds((const __attribute__((address_space(1))) void*)gp,
                                     (__attribute__((address_space(3))) void*)lp, 16, 0, 0);
}

// stage one 128x32 tile from src (row-major, row stride strideK shorts)
__device__ __forceinline__ void stage_sw(const unsigned short* src, int strideK,
                                         int rowMax, unsigned short* lds, int tid) {
#pragma unroll
    for (int rr = 0; rr < 2; ++rr) {
        int c = rr * 256 + tid;          // 0..511
        int p = c >> 3;
        int ci = (c & 7) ^ (p & 7);      // logical chunk stored at this slot
        int row = 2 * p + (ci >> 2);
        if (row > rowMax) row = rowMax;
        async_cp16(src + (long)row * strideK + (ci & 3) * 8, lds + c * 8);
    }
}

// XCD-aware block mapping: 4 n-tiles of one m-tile land on one XCD consecutively
__device__ __forceinline__ bool map_block(int b, int M, int& m0, int& n0) {
    int x = b & 7, slot = b >> 3;
    int mt = x + 8 * (slot >> 2);
    m0 = mt * 128; n0 = (slot & 3) * 128;
    return m0 < M;
}

// ---- GEMM1: C[M,512] = bf16(leaky(A[M,K] @ Bt[512,K]^T + bias)) ----
__global__ __launch_bounds__(256) void k_gemm_bf16(const unsigned short* __restrict__ A,
                                                   const unsigned short* __restrict__ Bt,
                                                   const float* __restrict__ bias,
                                                   unsigned short* __restrict__ C,
                                                   int M, int K) {
    __shared__ __align__(16) unsigned short As[128 * 32];
    __shared__ __align__(16) unsigned short Bs[128 * 32];
    const int tid  = threadIdx.x;
    const int lane = tid & 63, wave = tid >> 6;
    int m0, n0;
    if (!map_block(blockIdx.x, M, m0, n0)) return;
    const int r = lane & 15, q = lane >> 4;
    const int rh = r >> 1;
    const int sa = (((r & 1) << 2) | q) ^ rh;      // swizzled 16B-chunk slot
    const int wm = (wave & 1) * 64, wn = (wave >> 1) * 64;

    floatx4 acc[4][4];
#pragma unroll
    for (int i = 0; i < 4; ++i)
#pragma unroll
        for (int j = 0; j < 4; ++j) acc[i][j] = (floatx4){0.f, 0.f, 0.f, 0.f};

    for (int k0 = 0; k0 < K; k0 += 32) {
        stage_sw(A + (long)m0 * K + k0, K, M - 1 - m0, As, tid);
        stage_sw(Bt + (long)n0 * K + k0, K, 127, Bs, tid);
        __syncthreads();

        short8 af[4], bf[4];
#pragma unroll
        for (int i = 0; i < 4; ++i)
            af[i] = *(const short8*)(As + (wm / 2 + i * 8 + rh) * 64 + sa * 8);
#pragma unroll
        for (int j = 0; j < 4; ++j)
            bf[j] = *(const short8*)(Bs + (wn / 2 + j * 8 + rh) * 64 + sa * 8);
#pragma unroll
        for (int i = 0; i < 4; ++i)
#pragma unroll
            for (int j = 0; j < 4; ++j)
                acc[i][j] = __builtin_amdgcn_mfma_f32_16x16x32_bf16(af[i], bf[j], acc[i][j], 0, 0, 0);
        __syncthreads();
    }

    // C/D map: col = lane&15, row = q*4 + reg
#pragma unroll
    for (int j = 0; j < 4; ++j) {
        int col = n0 + wn + j * 16 + r;
        float bv = bias[col];
#pragma unroll
        for (int i = 0; i < 4; ++i) {
#pragma unroll
            for (int t2 = 0; t2 < 4; ++t2) {
                int row = m0 + wm + i * 16 + q * 4 + t2;
                if (row < M) {
                    float v = acc[i][j][t2] + bv;
                    v = v > 0.f ? v : NEG_SLOPE * v;
                    C[(long)row * D_HID + col] = f2bf(v);
                }
            }
        }
    }
}

// ---- GEMM2 fused with head: outacc[row] += sum_col leaky(A@Bt^T + b2) * wout[col] ----
__global__ __launch_bounds__(256) void k_gemm2f(const unsigned short* __restrict__ A,
                                                const unsigned short* __restrict__ Bt,
                                                const float* __restrict__ bias,
                                                const float* __restrict__ wout,
                                                float* __restrict__ outacc,
                                                int M, int K) {
    __shared__ __align__(16) unsigned short As[128 * 32];
    __shared__ __align__(16) unsigned short Bs[128 * 32];
    const int tid  = threadIdx.x;
    const int lane = tid & 63, wave = tid >> 6;
    int m0, n0;
    if (!map_block(blockIdx.x, M, m0, n0)) return;
    const int r = lane & 15, q = lane >> 4;
    const int rh = r >> 1;
    const int sa = (((r & 1) << 2) | q) ^ rh;
    const int wm = (wave & 1) * 64, wn = (wave >> 1) * 64;

    floatx4 acc[4][4];
#pragma unroll
    for (int i = 0; i < 4; ++i)
#pragma unroll
        for (int j = 0; j < 4; ++j) acc[i][j] = (floatx4){0.f, 0.f, 0.f, 0.f};

    for (int k0 = 0; k0 < K; k0 += 32) {
        stage_sw(A + (long)m0 * K + k0, K, M - 1 - m0, As, tid);
        stage_sw(Bt + (long)n0 * K + k0, K, 127, Bs, tid);
        __syncthreads();

        short8 af[4], bf[4];
#pragma unroll
        for (int i = 0; i < 4; ++i)
            af[i] = *(const short8*)(As + (wm / 2 + i * 8 + rh) * 64 + sa * 8);
#pragma unroll
        for (int j = 0; j < 4; ++j)
            bf[j] = *(const short8*)(Bs + (wn / 2 + j * 8 + rh) * 64 + sa * 8);
#pragma unroll
        for (int i = 0; i < 4; ++i)
#pragma unroll
            for (int j = 0; j < 4; ++j)
                acc[i][j] = __builtin_amdgcn_mfma_f32_16x16x32_bf16(af[i], bf[j], acc[i][j], 0, 0, 0);
        __syncthreads();
    }

    // fused epilogue: bias + leaky + dot with wout, shfl-reduce over 16 cols, atomic per row
    float bv[4], wv[4];
#pragma unroll
    for (int j = 0; j < 4; ++j) {
        int col = n0 + wn + j * 16 + r;
        bv[j] = bias[col];
        wv[j] = wout[col];
    }
#pragma unroll
    for (int i = 0; i < 4; ++i) {
#pragma unroll
        for (int t2 = 0; t2 < 4; ++t2) {
            float p = 0.f;
#pragma unroll
            for (int j = 0; j < 4; ++j) {
                float v = acc[i][j][t2] + bv[j];
                v = v > 0.f ? v : NEG_SLOPE * v;
                p += v * wv[j];
            }
            p += __shfl_xor(p, 8, 64);
            p += __shfl_xor(p, 4, 64);
            p += __shfl_xor(p, 2, 64);
            p += __shfl_xor(p, 1, 64);
            if (r == 0) {
                int row = m0 + wm + i * 16 + q * 4 + t2;
                if (row < M) atomicAdd(&outacc[row], p);
            }
        }
    }
}

// ---- final: plain-store copy outacc (ws) -> d_out ----
__global__ void k_out(const float* __restrict__ outacc, float* __restrict__ out, int N) {
    int i = blockIdx.x * blockDim.x + threadIdx.x;
    if (i < N) out[i] = outacc[i];
}

extern "C" void kernel_launch(void* const* d_in, const int* in_sizes, int n_in,
                              void* d_out, int out_size, void* d_ws, size_t ws_size,
                              hipStream_t stream) {
    const float* x     = (const float*)d_in[0];
    const void*  ei    = d_in[1];
    const float* W_gcn = (const float*)d_in[2];
    const float* b_gcn = (const float*)d_in[3];
    const float* W2    = (const float*)d_in[4];
    const float* b2    = (const float*)d_in[5];
    const float* W_out = (const float*)d_in[6];
    const float* b_out = (const float*)d_in[7];
    float* out = (float*)d_out;

    const int N = in_sizes[0] / D_IN;
    const int E = in_sizes[1] / 2;
    const int NB = (N + SCAN_CHUNK - 1) / SCAN_CHUNK;

    char* w = (char*)d_ws;
    size_t off = 0;
    auto alloc = [&](size_t bytes) { char* p = w + off; off = (off + bytes + 255) & ~(size_t)255; return p; };
    int*            flag   = (int*)alloc(256);
    float*          dinv   = (float*)alloc((size_t)N * 4);
    int*            deg_i  = (int*)alloc((size_t)N * 4);
    int*            offs   = (int*)alloc((size_t)(N + 1) * 4);
    int*            cursor = (int*)alloc((size_t)N * 4);
    float*          outacc = (float*)alloc((size_t)N * 4);
    int*            bsum   = (int*)alloc((size_t)NB * 4);
    int*            bbase  = (int*)alloc((size_t)NB * 4);
    int*            esrc   = (int*)alloc((size_t)E * 4);
    unsigned short* xb     = (unsigned short*)alloc((size_t)N * D_IN * 2);
    unsigned short* aggb   = (unsigned short*)alloc((size_t)N * D_IN * 2);
    unsigned short* h1     = (unsigned short*)alloc((size_t)N * D_HID * 2);
    unsigned short* Wgt    = (unsigned short*)alloc((size_t)D_IN * D_HID * 2);
    unsigned short* W2t    = (unsigned short*)alloc((size_t)D_HID * D_HID * 2);

    int npairs = E < 2048 ? E : 2048;
    long xthreads = ((long)N * D_IN) / 4;
    k_init<<<(unsigned)((xthreads + 255) / 256), 256, 0, stream>>>(
        x, xb, deg_i, N, (const unsigned int*)ei, npairs, flag);

    k_deg_count<<<(E + 255) / 256, 256, 0, stream>>>(ei, flag, deg_i, E);
    k_scan1<<<NB, 256, 0, stream>>>(deg_i, bsum, N);
    k_scan2<<<1, 1024, 0, stream>>>(bsum, bbase, offs, NB, N);
    k_scan3<<<NB, 256, 0, stream>>>(deg_i, bbase, offs, cursor, dinv, N);
    k_fill<<<(E + 255) / 256, 256, 0, stream>>>(ei, flag, cursor, esrc, E);
    k_gather<<<(N + 3) / 4, 256, 0, stream>>>(xb, offs, esrc, dinv, aggb, N);

    int prep_threads = D_IN * D_HID + D_HID * D_HID + N;
    k_prep<<<(prep_threads + 255) / 256, 256, 0, stream>>>(W_gcn, Wgt, W2, W2t, b_out, outacc, N);

    int mtiles = (N + 127) / 128;
    int gblocks = ((mtiles + 7) / 8) * 8 * 4;
    k_gemm_bf16<<<gblocks, 256, 0, stream>>>(aggb, Wgt, b_gcn, h1, N, D_IN);
    k_gemm2f<<<gblocks, 256, 0, stream>>>(h1, W2t, b2, W_out, outacc, N, D_HID);

    k_out<<<(N + 255) / 256, 256, 0, stream>>>(outacc, out, N);
}